// Round 12
// baseline (90.728 us; speedup 1.0000x reference)
//
#include <hip/hip_runtime.h>

// VIN, R12 = R11 + instruction/latency trims:
//  - v_max3_f32 reduction tree (4 ops/scalar vs 7)
//  - all global loads (X tile, Wq->SGPR pairs, S1/S2) hoisted to kernel top so
//    cold-HBM latency overlaps LDS zeroing + weff contraction
// Core (verified): 2-WG redundant-halo row trapezoid; 144 v_pk_fma_f32/step
// (SGPR-pair weights via op_sel dword select), DPP horizontal halo, b64
// band-boundary LDS ping-pong, 1 barrier/step, phase-split LDS consumption.
// Rejected by arithmetic: >2 WGs (interior strips need >=57 rows), col splits
// (DPP is intra-wave), k-step local trapezoids (+25% FMA > barrier savings).

#define ACT 8
#define HID 150
#define STR 76
#define NB   26          // row-pair bands per WG
#define NTHR (NB * 32)   // 832 threads = 13 waves

typedef float v2f __attribute__((ext_vector_type(2)));
typedef unsigned long long u64;

__device__ __forceinline__ void pkfma_lo(v2f& acc, u64 wp, v2f x) {
  asm("v_pk_fma_f32 %0, %1, %2, %0 op_sel:[0,0,0] op_sel_hi:[0,1,1]"
      : "+v"(acc) : "s"(wp), "v"(x));
}
__device__ __forceinline__ void pkfma_hi(v2f& acc, u64 wp, v2f x) {
  asm("v_pk_fma_f32 %0, %1, %2, %0 op_sel:[1,0,0] op_sel_hi:[1,1,1]"
      : "+v"(acc) : "s"(wp), "v"(x));
}
__device__ __forceinline__ void pkfma_s(v2f& acc, u64 wp, int half, v2f x) {
  if (half == 0) pkfma_lo(acc, wp, x); else pkfma_hi(acc, wp, x);
}
__device__ __forceinline__ float max3(float a, float b, float c) {
  float d;
  asm("v_max3_f32 %0, %1, %2, %3" : "=v"(d) : "v"(a), "v"(b), "v"(c));
  return d;
}
__device__ __forceinline__ v2f cmax(v2f a, v2f b) {
  return (v2f){fmaxf(a.x, b.x), fmaxf(a.y, b.y)};
}
__device__ __forceinline__ v2f cfma(float w, v2f x, v2f acc) {
  acc.x = fmaf(w, x.x, acc.x);
  acc.y = fmaf(w, x.y, acc.y);
  return acc;
}
// max over 8 v2f: per scalar = max3,max3,max, then max3 (4 ops)
__device__ __forceinline__ v2f max8(const v2f (&q)[ACT]) {
  v2f r;
  r.x = max3(max3(q[0].x, q[1].x, q[2].x), max3(q[3].x, q[4].x, q[5].x),
             fmaxf(q[6].x, q[7].x));
  r.y = max3(max3(q[0].y, q[1].y, q[2].y), max3(q[3].y, q[4].y, q[5].y),
             fmaxf(q[6].y, q[7].y));
  return r;
}
__device__ __forceinline__ float uload(const float* p) {  // wave-uniform only
  return __int_as_float(__builtin_amdgcn_readfirstlane(__float_as_int(*p)));
}
__device__ __forceinline__ float lane_prev(float x) {  // wave_shr:1, lane0->0
  return __int_as_float(
      __builtin_amdgcn_update_dpp(0, __float_as_int(x), 0x138, 0xF, 0xF, true));
}
__device__ __forceinline__ float lane_next(float x) {  // wave_shl:1, lane63->0
  return __int_as_float(
      __builtin_amdgcn_update_dpp(0, __float_as_int(x), 0x130, 0xF, 0xF, true));
}

__launch_bounds__(NTHR, 4)
__global__ void vin_kernel(const float* __restrict__ X,
                           const int*   __restrict__ S1,
                           const int*   __restrict__ S2,
                           const float* __restrict__ Wh,
                           const float* __restrict__ bh,
                           const float* __restrict__ Wr,
                           const float* __restrict__ Wq,
                           float*       __restrict__ out) {
  __shared__ float r_s[54][STR];       // local rows -1..52 (index = local+1)
  __shared__ float v_s[54][STR];       // v19, same indexing
  __shared__ v2f   tb[2][28][32];      // ping-pong: band top rows (+halo 0,27)
  __shared__ v2f   bb[2][28][32];      // ping-pong: band bottom rows
  __shared__ float weff_s[19];
  __shared__ int   s12_s[128];

  const int tid  = threadIdx.x;
  const int tx   = tid & 31;
  const int ty   = tid >> 5;           // 0..25
  const int lane = tid & 63;
  const float zp = (lane == 32) ? 0.f : 1.f;   // mid-wave band-crossing fixups
  const float zn = (lane == 31) ? 0.f : 1.f;
  const int Rl = ty << 1;              // local row of band top
  const int cc = tx << 1;
  const int wg = blockIdx.x;           // 0 or 1
  const int B  = wg * 12;              // global row base (WG1: rows 12..63)

  // ==== HOISTED GLOBAL LOADS (issue before anything else; latency overlaps
  //      LDS zeroing + weff contraction) ====
  v2f xx[2][4];
  #pragma unroll
  for (int ch = 0; ch < 2; ++ch)
    #pragma unroll
    for (int dy = 0; dy < 4; ++dy) {
      const int g = B + Rl - 1 + dy;    // global row
      xx[ch][dy] = (g >= 0 && g < 64)
                 ? *(const v2f*)&X[ch * 4096 + g * 64 + cc]
                 : (v2f){0.f, 0.f};
    }
  // VI weights: 2 consecutive weights per SGPR pair (72 loads, L2-warming)
  u64 wqp[36];
  #pragma unroll
  for (int p = 0; p < 36; ++p) {
    const int w0 = 2 * p, w1 = 2 * p + 1;   // weight idx = a*9 + t
    const unsigned lo = (unsigned)__builtin_amdgcn_readfirstlane(
        __float_as_int(Wq[(w0 / 9) * 18 + 9 + (w0 % 9)]));
    const unsigned hi = (unsigned)__builtin_amdgcn_readfirstlane(
        __float_as_int(Wq[(w1 / 9) * 18 + 9 + (w1 % 9)]));
    wqp[p] = (u64)lo | ((u64)hi << 32);
  }
  if (tid < 128) s12_s[tid] = (tid < 64) ? S1[tid] : S2[tid - 64];

  { // zero LDS (halos must be 0)
    const float4 z = make_float4(0.f, 0.f, 0.f, 0.f);
    float4* a = (float4*)&r_s[0][0];
    for (int i = tid; i < 54 * STR / 4; i += NTHR) a[i] = z;
    float4* b = (float4*)&v_s[0][0];
    for (int i = tid; i < 54 * STR / 4; i += NTHR) b[i] = z;
    float4* c = (float4*)&tb[0][0][0];
    for (int i = tid; i < 2 * 28 * 32 / 2; i += NTHR) c[i] = z;
    float4* d = (float4*)&bb[0][0][0];
    for (int i = tid; i < 2 * 28 * 32 / 2; i += NTHR) d[i] = z;
  }

  // weff contraction: 19 outputs x 32 lanes
  if (tid < 19 * 32) {
    const int t = tid >> 5, ln = tid & 31;
    float acc = 0.f;
    #pragma unroll
    for (int i = 0; i < 5; ++i) {
      const int h = ln + 32 * i;
      if (h < HID) acc += Wr[h] * (t < 18 ? Wh[h * 18 + t] : bh[h]);
    }
    acc += __shfl_xor(acc, 1);
    acc += __shfl_xor(acc, 2);
    acc += __shfl_xor(acc, 4);
    acc += __shfl_xor(acc, 8);
    acc += __shfl_xor(acc, 16);
    if (ln == 0) weff_s[t] = acc;
  }
  __syncthreads();

  // ---- stage 1: r EXACT on local rows 0..51 (X already in registers) ----
  v2f ra, rb;
  {
    float wl[18];
    #pragma unroll
    for (int t = 0; t < 18; ++t) wl[t] = uload(&weff_s[t]);
    const float beff = uload(&weff_s[18]);
    v2f a0 = (v2f){beff, beff}, a1 = a0;
    #pragma unroll
    for (int ch = 0; ch < 2; ++ch) {
      v2f L[4], Rr[4];
      #pragma unroll
      for (int i = 0; i < 4; ++i) {
        L[i]  = (v2f){lane_prev(xx[ch][i].y) * zp, xx[ch][i].x};
        Rr[i] = (v2f){xx[ch][i].y, lane_next(xx[ch][i].x) * zn};
      }
      #pragma unroll
      for (int dy = 0; dy < 3; ++dy) {
        const float w0 = wl[ch * 9 + dy * 3 + 0];
        const float w1 = wl[ch * 9 + dy * 3 + 1];
        const float w2 = wl[ch * 9 + dy * 3 + 2];
        a0 = cfma(w0, L[dy], a0);     a0 = cfma(w1, xx[ch][dy], a0);
        a0 = cfma(w2, Rr[dy], a0);
        a1 = cfma(w0, L[dy + 1], a1); a1 = cfma(w1, xx[ch][dy + 1], a1);
        a1 = cfma(w2, Rr[dy + 1], a1);
      }
    }
    *(v2f*)&r_s[Rl + 1][cc + 4] = a0;
    *(v2f*)&r_s[Rl + 2][cc + 4] = a1;
    ra = a0; rb = a1;
  }
  __syncthreads();

  // ---- stage 2: qr (iteration-invariant); v1 = max_a qr ----
  v2f qr0[ACT], qr1[ACT], v0, v1;
  {
    v2f rows[4];
    rows[0] = *(const v2f*)&r_s[Rl][cc + 4];
    rows[1] = ra;
    rows[2] = rb;
    rows[3] = *(const v2f*)&r_s[Rl + 3][cc + 4];
    v2f L[4], Rr[4];
    #pragma unroll
    for (int i = 0; i < 4; ++i) {
      L[i]  = (v2f){lane_prev(rows[i].y) * zp, rows[i].x};
      Rr[i] = (v2f){rows[i].y, lane_next(rows[i].x) * zn};
    }
    #pragma unroll
    for (int a = 0; a < ACT; ++a) {
      v2f q0 = (v2f){0.f, 0.f}, q1 = (v2f){0.f, 0.f};
      #pragma unroll
      for (int dy = 0; dy < 3; ++dy) {
        const float w0 = uload(&Wq[a * 18 + dy * 3 + 0]);
        const float w1 = uload(&Wq[a * 18 + dy * 3 + 1]);
        const float w2 = uload(&Wq[a * 18 + dy * 3 + 2]);
        q0 = cfma(w0, L[dy], q0);     q0 = cfma(w1, rows[dy], q0);
        q0 = cfma(w2, Rr[dy], q0);
        q1 = cfma(w0, L[dy + 1], q1); q1 = cfma(w1, rows[dy + 1], q1);
        q1 = cfma(w2, Rr[dy + 1], q1);
      }
      qr0[a] = q0; qr1[a] = q1;
      v0 = a ? cmax(v0, q0) : q0;
      v1 = a ? cmax(v1, q1) : q1;
    }
    tb[0][ty + 1][tx] = v0;
    bb[0][ty + 1][tx] = v1;
  }
  __syncthreads();

  // ---- stage 3: 18 VI steps, trapezoid-predicated, phase-split ----
  auto vi = [&](int s, int p) {
    const bool act = (wg == 0) ? (Rl <= 49 - s) : (Rl >= s + 1);
    if (act) {
      // issue boundary reads first; consume them only in phase 2
      const v2f r0 = bb[p][ty][tx];        // row 2ty-1 (halo row 0 = zeros)
      const v2f r3 = tb[p][ty + 2][tx];    // row 2ty+2 (halo row 27 = zeros)

      // mid-row packs (registers only)
      v2f L1 = (v2f){lane_prev(v0.y) * zp, v0.x};
      v2f R1 = (v2f){v0.y, lane_next(v0.x) * zn};
      v2f L2 = (v2f){lane_prev(v1.y) * zp, v1.x};
      v2f R2 = (v2f){v1.y, lane_next(v1.x) * zn};

      v2f qq0[ACT], qq1[ACT];
      // phase 1: 96 pkfma on register rows only
      #pragma unroll
      for (int a = 0; a < ACT; ++a) {
        v2f q0 = qr0[a], q1 = qr1[a];
        const int i10 = a * 9 + 3, i11 = a * 9 + 4, i12 = a * 9 + 5;
        const int i20 = a * 9 + 6, i21 = a * 9 + 7, i22 = a * 9 + 8;
        const int i00 = a * 9 + 0, i01 = a * 9 + 1, i02 = a * 9 + 2;
        pkfma_s(q0, wqp[i10 >> 1], i10 & 1, L1);
        pkfma_s(q0, wqp[i11 >> 1], i11 & 1, v0);
        pkfma_s(q0, wqp[i12 >> 1], i12 & 1, R1);
        pkfma_s(q0, wqp[i20 >> 1], i20 & 1, L2);
        pkfma_s(q0, wqp[i21 >> 1], i21 & 1, v1);
        pkfma_s(q0, wqp[i22 >> 1], i22 & 1, R2);
        pkfma_s(q1, wqp[i00 >> 1], i00 & 1, L1);
        pkfma_s(q1, wqp[i01 >> 1], i01 & 1, v0);
        pkfma_s(q1, wqp[i02 >> 1], i02 & 1, R1);
        pkfma_s(q1, wqp[i10 >> 1], i10 & 1, L2);
        pkfma_s(q1, wqp[i11 >> 1], i11 & 1, v1);
        pkfma_s(q1, wqp[i12 >> 1], i12 & 1, R2);
        qq0[a] = q0; qq1[a] = q1;
      }

      // phase 2: LDS-row packs + remaining 48 pkfma
      v2f L0 = (v2f){lane_prev(r0.y) * zp, r0.x};
      v2f R0 = (v2f){r0.y, lane_next(r0.x) * zn};
      v2f L3 = (v2f){lane_prev(r3.y) * zp, r3.x};
      v2f R3 = (v2f){r3.y, lane_next(r3.x) * zn};
      #pragma unroll
      for (int a = 0; a < ACT; ++a) {
        const int i00 = a * 9 + 0, i01 = a * 9 + 1, i02 = a * 9 + 2;
        const int i20 = a * 9 + 6, i21 = a * 9 + 7, i22 = a * 9 + 8;
        pkfma_s(qq0[a], wqp[i00 >> 1], i00 & 1, L0);
        pkfma_s(qq0[a], wqp[i01 >> 1], i01 & 1, r0);
        pkfma_s(qq0[a], wqp[i02 >> 1], i02 & 1, R0);
        pkfma_s(qq1[a], wqp[i20 >> 1], i20 & 1, L3);
        pkfma_s(qq1[a], wqp[i21 >> 1], i21 & 1, r3);
        pkfma_s(qq1[a], wqp[i22 >> 1], i22 & 1, R3);
      }
      v0 = max8(qq0);
      v1 = max8(qq1);
      tb[p ^ 1][ty + 1][tx] = v0;
      bb[p ^ 1][ty + 1][tx] = v1;
    }
    __syncthreads();
  };
  #pragma unroll 1
  for (int it = 0; it < 9; ++it) {
    vi(2 * it, 0);
    vi(2 * it + 1, 1);
  }

  // v19 -> v_s (garbage rows written too; reads stay in each WG's valid zone)
  *(v2f*)&v_s[Rl + 1][cc + 4] = v0;
  *(v2f*)&v_s[Rl + 2][cc + 4] = v1;
  __syncthreads();

  // ---- stage 4: queries split by row half; per-lane Wq loads (a not uniform) ----
  if (tid < 64 * ACT) {
    const int k = tid >> 3;
    const int a = tid & 7;
    const int qy = s12_s[k];
    const int qx = s12_s[64 + k];
    const bool mine = (wg == 0) ? (qy <= 31) : (qy >= 32);
    const int ly = mine ? (qy - B) : 25;   // safe in-bounds dummy when !mine
    float accq = 0.f;
    #pragma unroll
    for (int dy = 0; dy < 3; ++dy)
      #pragma unroll
      for (int dx = 0; dx < 3; ++dx) {
        const float w0 = Wq[a * 18 + dy * 3 + dx];
        const float w1 = Wq[a * 18 + 9 + dy * 3 + dx];
        accq += w0 * r_s[ly + dy][qx + dx + 3];
        accq += w1 * v_s[ly + dy][qx + dx + 3];
      }
    float m = accq;
    m = fmaxf(m, __shfl_xor(m, 1));
    m = fmaxf(m, __shfl_xor(m, 2));
    m = fmaxf(m, __shfl_xor(m, 4));
    const float e = __expf(accq - m);
    float s = e;
    s += __shfl_xor(s, 1);
    s += __shfl_xor(s, 2);
    s += __shfl_xor(s, 4);
    if (mine) out[tid] = e / s;
  }
}

extern "C" void kernel_launch(void* const* d_in, const int* in_sizes, int n_in,
                              void* d_out, int out_size, void* d_ws, size_t ws_size,
                              hipStream_t stream) {
  const float* X  = (const float*)d_in[0];
  const int*   S1 = (const int*)d_in[1];
  const int*   S2 = (const int*)d_in[2];
  const float* Wh = (const float*)d_in[3];
  const float* bh = (const float*)d_in[4];
  const float* Wr = (const float*)d_in[5];
  const float* Wq = (const float*)d_in[6];
  float* out = (float*)d_out;

  vin_kernel<<<2, NTHR, 0, stream>>>(X, S1, S2, Wh, bh, Wr, Wq, out);
}